// Round 7
// baseline (544.918 us; speedup 1.0000x reference)
//
#include <hip/hip_runtime.h>
#include <math.h>

// TokenChoiceTopKRouter, round 7: B-stationary-in-LDS MFMA GEMM, K-split
// with global partials.
//
// R6 lesson: B-frag stream re-read per wave = 1 GB cross-XCD L3 traffic,
// depth-1 prefetch -> 319 GB/s, latency-bound. Fix:
//  k1 pack_w: w -> d_ws B-frag stream (hi/lo bf16, mfma_16x16x32 lane layout,
//     grouped by K-slice). Same proven numerics/layout as R6 (absmax 50).
//  k2: grid = 8 ks x (ntok/512) tg. Block stages its 128 KB B-slice into LDS
//     ONCE (ks == blockIdx&7 == XCD id -> B L2-local), then ZERO barriers:
//     8 waves x 4 tiles x 16 steps, depth-6 x prefetch (96 KB/CU in flight),
//     split x to hi/lo bf16 in-reg, 12 MFMA/step, B via conflict-free
//     ds_read_b128. Partials -> ws[ks][t][e] (32 MB, non-atomic).
//  k3: reduce 8 slices per token + sigmoid + biased top-8 + normalize +
//     histogram (proven tail).
// Fallbacks: ws < 34 MB -> R6 proven path; ws < 1 MB -> R5 fp32 path.

constexpr int DIM = 4096;
constexpr int NE  = 64;
constexpr size_t WSB_BYTES = 1048576;            // packed B stream (1 MB)

typedef __attribute__((ext_vector_type(8))) short bf16x8;
typedef __attribute__((ext_vector_type(4))) float f32x4;

// ---------- k1: pack w into per-K-slice hi/lo B-fragment stream ----------
// 16B-unit u = ks*8192 + sl*512 + f*64 + lane, f = et*2 + hl.
// Content: e = et*16 + (lane&15), k = ks*512 + sl*32 + 8*(lane>>4) (+j).
__global__ void pack_w(const float* __restrict__ w, ushort* __restrict__ wsB) {
  const int u  = blockIdx.x * 256 + threadIdx.x;   // 65536 units
  const int l  = u & 63;
  const int f  = (u >> 6) & 7;
  const int sl = (u >> 9) & 15;
  const int ks = u >> 13;
  const int et = f >> 1, hl = f & 1;
  const int e  = et * 16 + (l & 15);
  const int k  = ks * 512 + sl * 32 + 8 * (l >> 4);
  const float* src = w + (size_t)e * DIM + k;
  ushort v[8];
#pragma unroll
  for (int j = 0; j < 8; ++j) {
    float xv = src[j];
    unsigned xb = __float_as_uint(xv);
    unsigned hb = xb & 0xffff0000u;                // exact hi (truncation)
    if (hl == 0) {
      v[j] = (ushort)(hb >> 16);
    } else {
      float lf = xv - __uint_as_float(hb);
      unsigned lb = __float_as_uint(lf);
      lb = lb + 0x7fffu + ((lb >> 16) & 1u);       // RNE to bf16
      v[j] = (ushort)(lb >> 16);
    }
  }
  ushort* d = wsB + (size_t)u * 8;
#pragma unroll
  for (int j = 0; j < 8; ++j) d[j] = v[j];
}

// ---------- shared helper: f32x8 -> hi/lo bf16x8 ----------
__device__ __forceinline__ void split8(const float4& a0, const float4& a1,
                                       bf16x8& ahi, bf16x8& alo) {
  float av[8] = {a0.x, a0.y, a0.z, a0.w, a1.x, a1.y, a1.z, a1.w};
#pragma unroll
  for (int j = 0; j < 8; ++j) {
    unsigned xb = __float_as_uint(av[j]);
    unsigned hb = xb & 0xffff0000u;
    float lf = av[j] - __uint_as_float(hb);
    unsigned lb = __float_as_uint(lf);
    lb = lb + 0x7fffu + ((lb >> 16) & 1u);
    ahi[j] = (short)(hb >> 16);
    alo[j] = (short)(lb >> 16);
  }
}

// ---------- k2: main GEMM, B stationary in LDS, partials to ws ----------
__global__ __launch_bounds__(512, 1)
void router_k2(const float* __restrict__ x, const uint4* __restrict__ wsB,
               float* __restrict__ wsP, int ntok) {
  __shared__ uint4 ldsB[8192];                    // 128 KB B-slice
  const int tid  = threadIdx.x;
  const int ks   = blockIdx.x & 7;                // == XCD id (L2-local B)
  const int tg   = blockIdx.x >> 3;
  const int wave = tid >> 6;
  const int lane = tid & 63;
  const int col  = lane & 15;                     // token col / expert col
  const int kq   = lane >> 4;                     // k-quad

  // stage B-slice once (coalesced global, linear LDS)
  const uint4* src = wsB + (size_t)ks * 8192;
#pragma unroll
  for (int it = 0; it < 16; ++it) ldsB[it * 512 + tid] = src[it * 512 + tid];
  __syncthreads();

  const bf16x8* B16 = (const bf16x8*)ldsB;
  const int t0w = tg * 512 + wave * 64;

#pragma unroll 1
  for (int tile = 0; tile < 4; ++tile) {
    const int t0 = t0w + tile * 16;
    const float* xr = x + (size_t)(t0 + col) * DIM + ks * 512 + 8 * kq;

    f32x4 acc[4];
#pragma unroll
    for (int et = 0; et < 4; ++et) acc[et] = (f32x4){0.f, 0.f, 0.f, 0.f};

    float4 pa[16], pb[16];                        // static-indexed (full unroll)
#pragma unroll
    for (int s = 0; s < 6; ++s) {                 // prologue: depth-6 prefetch
      pa[s] = *(const float4*)(xr + s * 32);
      pb[s] = *(const float4*)(xr + s * 32 + 4);
    }

#pragma unroll
    for (int s = 0; s < 16; ++s) {
      if (s + 6 < 16) {
        pa[s + 6] = *(const float4*)(xr + (s + 6) * 32);
        pb[s + 6] = *(const float4*)(xr + (s + 6) * 32 + 4);
      }
      bf16x8 ahi, alo;
      split8(pa[s], pb[s], ahi, alo);
#pragma unroll
      for (int et = 0; et < 4; ++et) {
        bf16x8 bh = B16[(s * 8 + et * 2 + 0) * 64 + lane];
        bf16x8 bl = B16[(s * 8 + et * 2 + 1) * 64 + lane];
        acc[et] = __builtin_amdgcn_mfma_f32_16x16x32_bf16(ahi, bh, acc[et], 0, 0, 0);
        acc[et] = __builtin_amdgcn_mfma_f32_16x16x32_bf16(alo, bh, acc[et], 0, 0, 0);
        acc[et] = __builtin_amdgcn_mfma_f32_16x16x32_bf16(ahi, bl, acc[et], 0, 0, 0);
      }
    }

    // partials: D layout col=lane&15, row=4*kq+r (m89-verified, R6-proven)
    float* dst = wsP + (size_t)ks * ntok * 64;
#pragma unroll
    for (int et = 0; et < 4; ++et)
#pragma unroll
      for (int r = 0; r < 4; ++r)
        dst[(size_t)(t0 + 4 * kq + r) * 64 + et * 16 + col] = acc[et][r];
  }
}

// ---------- k3: reduce K-slices + sigmoid + top-8 + normalize + histogram --
__global__ __launch_bounds__(128)
void router_k3(const float* __restrict__ wsP, const float* __restrict__ bias,
               float* __restrict__ out_scores, float* __restrict__ out_idx,
               float* __restrict__ counts, int ntok) {
  const int t = blockIdx.x * 128 + threadIdx.x;
  float a[64];
#pragma unroll
  for (int j = 0; j < 16; ++j) {
    f32x4 v = *(const f32x4*)(wsP + (size_t)t * 64 + j * 4);
    a[4 * j + 0] = v[0]; a[4 * j + 1] = v[1];
    a[4 * j + 2] = v[2]; a[4 * j + 3] = v[3];
  }
#pragma unroll
  for (int ks = 1; ks < 8; ++ks) {
#pragma unroll
    for (int j = 0; j < 16; ++j) {
      f32x4 v = *(const f32x4*)(wsP + (size_t)ks * ntok * 64 + (size_t)t * 64 + j * 4);
      a[4 * j + 0] += v[0]; a[4 * j + 1] += v[1];
      a[4 * j + 2] += v[2]; a[4 * j + 3] += v[3];
    }
  }

  float key[8], sv[8];
  int   idx[8];
#pragma unroll
  for (int j = 0; j < 8; ++j) { key[j] = -1e30f; sv[j] = 0.f; idx[j] = 0; }

#pragma unroll
  for (int e = 0; e < NE; ++e) {
    float s = 1.0f / (1.0f + expf(-a[e]));
    float k = s + bias[e];
    // bubble-insert; strict > keeps lower index on ties (lax.top_k order)
    float ck = k, cv = s; int ci = e;
#pragma unroll
    for (int j = 0; j < 8; ++j) {
      bool g = ck > key[j];
      float tk = key[j], tv = sv[j]; int ti = idx[j];
      key[j] = g ? ck : tk; sv[j] = g ? cv : tv; idx[j] = g ? ci : ti;
      ck = g ? tk : ck;     cv = g ? tv : cv;    ci = g ? ti : ci;
    }
  }

  float sum = 1e-20f;
#pragma unroll
  for (int j = 0; j < 8; ++j) sum += sv[j];
  float inv = 1.0f / sum;
#pragma unroll
  for (int j = 0; j < 8; ++j) {
    out_scores[t * 8 + j] = sv[j] * inv;
    out_idx[t * 8 + j]    = (float)idx[j];
    atomicAdd(&counts[idx[j]], 1.0f);
  }
}

// ---------- R6 proven mid-fallback (ws >= 1 MB): direct B-stream MFMA ------
__global__ __launch_bounds__(512, 2)
void router_mfma(const float* __restrict__ x, const ushort* __restrict__ ws,
                 const float* __restrict__ bias,
                 float* __restrict__ out_scores, float* __restrict__ out_idx,
                 float* __restrict__ counts) {
  __shared__ float logits[64 * 64];
  const int tid  = threadIdx.x;
  const int lane = tid & 63;
  const int wv   = tid >> 6;
  const int wt   = wv & 3;
  const int wk   = wv >> 2;
  const int tok0 = blockIdx.x * 64;
  const int col  = lane & 15;
  const int kq   = lane >> 4;
  const float* xrow = x + (size_t)(tok0 + wt * 16 + col) * DIM + wk * 2048 + 8 * kq;
  const ushort* wsl = ws + (size_t)lane * 8;
  f32x4 acc[4];
#pragma unroll
  for (int et = 0; et < 4; ++et) acc[et] = (f32x4){0.f, 0.f, 0.f, 0.f};
  const int s0 = wk * 64;
  float4 a0c = *(const float4*)(xrow + 0);
  float4 a1c = *(const float4*)(xrow + 4);
  bf16x8 bc[8];
#pragma unroll
  for (int f = 0; f < 8; ++f)
    bc[f] = *(const bf16x8*)(wsl + (size_t)(s0 * 8 + f) * 64 * 8);
#pragma unroll 1
  for (int ls = 0; ls < 64; ls += 2) {
    const int so = s0 + ls + 1;
    float4 a0o = *(const float4*)(xrow + (ls + 1) * 32);
    float4 a1o = *(const float4*)(xrow + (ls + 1) * 32 + 4);
    bf16x8 bo[8];
#pragma unroll
    for (int f = 0; f < 8; ++f)
      bo[f] = *(const bf16x8*)(wsl + (size_t)(so * 8 + f) * 64 * 8);
    {
      bf16x8 ahi, alo;
      split8(a0c, a1c, ahi, alo);
#pragma unroll
      for (int et = 0; et < 4; ++et) {
        acc[et] = __builtin_amdgcn_mfma_f32_16x16x32_bf16(ahi, bc[et * 2 + 0], acc[et], 0, 0, 0);
        acc[et] = __builtin_amdgcn_mfma_f32_16x16x32_bf16(alo, bc[et * 2 + 0], acc[et], 0, 0, 0);
        acc[et] = __builtin_amdgcn_mfma_f32_16x16x32_bf16(ahi, bc[et * 2 + 1], acc[et], 0, 0, 0);
      }
    }
    if (ls + 2 < 64) {
      const int se = s0 + ls + 2;
      a0c = *(const float4*)(xrow + (ls + 2) * 32);
      a1c = *(const float4*)(xrow + (ls + 2) * 32 + 4);
#pragma unroll
      for (int f = 0; f < 8; ++f)
        bc[f] = *(const bf16x8*)(wsl + (size_t)(se * 8 + f) * 64 * 8);
    }
    {
      bf16x8 ahi, alo;
      split8(a0o, a1o, ahi, alo);
#pragma unroll
      for (int et = 0; et < 4; ++et) {
        acc[et] = __builtin_amdgcn_mfma_f32_16x16x32_bf16(ahi, bo[et * 2 + 0], acc[et], 0, 0, 0);
        acc[et] = __builtin_amdgcn_mfma_f32_16x16x32_bf16(alo, bo[et * 2 + 0], acc[et], 0, 0, 0);
        acc[et] = __builtin_amdgcn_mfma_f32_16x16x32_bf16(ahi, bo[et * 2 + 1], acc[et], 0, 0, 0);
      }
    }
  }
  if (wk == 0) {
#pragma unroll
    for (int et = 0; et < 4; ++et)
#pragma unroll
      for (int r = 0; r < 4; ++r) {
        int t = wt * 16 + 4 * kq + r;
        int e = et * 16 + col;
        logits[t * 64 + ((e + t) & 63)] = acc[et][r];
      }
  }
  __syncthreads();
  if (wk == 1) {
#pragma unroll
    for (int et = 0; et < 4; ++et)
#pragma unroll
      for (int r = 0; r < 4; ++r) {
        int t = wt * 16 + 4 * kq + r;
        int e = et * 16 + col;
        logits[t * 64 + ((e + t) & 63)] += acc[et][r];
      }
  }
  __syncthreads();
  if (tid < 64) {
    const int t = tid, gt = tok0 + t;
    float key[8], sv[8]; int idx[8];
#pragma unroll
    for (int j = 0; j < 8; ++j) { key[j] = -1e30f; sv[j] = 0.f; idx[j] = 0; }
    for (int e = 0; e < NE; ++e) {
      float l = logits[t * 64 + ((e + t) & 63)];
      float s = 1.0f / (1.0f + expf(-l));
      float k = s + bias[e];
      float ck = k, cv = s; int ci = e;
#pragma unroll
      for (int j = 0; j < 8; ++j) {
        bool g = ck > key[j];
        float tk = key[j], tv = sv[j]; int ti = idx[j];
        key[j] = g ? ck : tk; sv[j] = g ? cv : tv; idx[j] = g ? ci : ti;
        ck = g ? tk : ck;     cv = g ? tv : cv;    ci = g ? ti : ci;
      }
    }
    float sum = 1e-20f;
#pragma unroll
    for (int j = 0; j < 8; ++j) sum += sv[j];
    float inv = 1.0f / sum;
#pragma unroll
    for (int j = 0; j < 8; ++j) {
      out_scores[gt * 8 + j] = sv[j] * inv;
      out_idx[gt * 8 + j]    = (float)idx[j];
      atomicAdd(&counts[idx[j]], 1.0f);
    }
  }
}

// ---------- R5 proven last-resort fallback (fp32 scalar-w) ----------
constexpr int KSTEP = 32;
constexpr int FNSTEP = DIM / KSTEP;
constexpr int ROWF4 = 9;
constexpr int BUF4  = 64 * ROWF4;

__global__ __launch_bounds__(512, 2)
void router_fallback(const float* __restrict__ x, const float* __restrict__ w,
                     const float* __restrict__ bias,
                     float* __restrict__ out_scores, float* __restrict__ out_idx,
                     float* __restrict__ counts) {
  __shared__ float4 lds4[2 * BUF4];
  float* ldsf = (float*)lds4;
  const int tid  = threadIdx.x;
  const int lane = tid & 63;
  const int eg   = __builtin_amdgcn_readfirstlane(tid >> 6);
  const int tok0 = blockIdx.x * 64;
  const int r0 = tid >> 3, j0 = tid & 7;
  const float* gp = &x[(size_t)(tok0 + r0) * DIM + j0 * 4];
  const int l0 = r0 * ROWF4 + j0;
  float acc[8];
#pragma unroll
  for (int e = 0; e < 8; ++e) acc[e] = 0.f;
  lds4[l0] = *(const float4*)gp;
  __syncthreads();
  const float* wbase = w + (size_t)eg * 8 * DIM;
#pragma unroll 1
  for (int c = 0; c < FNSTEP; ++c) {
    float4 pf;
    if (c + 1 < FNSTEP) pf = *(const float4*)(gp + (c + 1) * KSTEP);
    float xr[KSTEP];
    {
      const float4* xrow = lds4 + (c & 1) * BUF4 + lane * ROWF4;
#pragma unroll
      for (int i = 0; i < 8; ++i) {
        float4 q = xrow[i];
        xr[4 * i + 0] = q.x; xr[4 * i + 1] = q.y;
        xr[4 * i + 2] = q.z; xr[4 * i + 3] = q.w;
      }
    }
#pragma unroll
    for (int e = 0; e < 8; ++e) {
      const float* wr = wbase + e * DIM + c * KSTEP;
#pragma unroll
      for (int k = 0; k < KSTEP; ++k) acc[e] = fmaf(xr[k], wr[k], acc[e]);
    }
    if (c + 1 < FNSTEP) lds4[((c + 1) & 1) * BUF4 + l0] = pf;
    __syncthreads();
  }
#pragma unroll
  for (int j = 0; j < 8; ++j) {
    int e = eg * 8 + j;
    ldsf[lane * 64 + ((e + lane) & 63)] = acc[j];
  }
  __syncthreads();
  if (tid < 64) {
    const int t = tid, gt = tok0 + t;
    float key[8], sv[8]; int idx[8];
#pragma unroll
    for (int j = 0; j < 8; ++j) { key[j] = -1e30f; sv[j] = 0.f; idx[j] = 0; }
    for (int e = 0; e < NE; ++e) {
      float l = ldsf[t * 64 + ((e + t) & 63)];
      float s = 1.0f / (1.0f + expf(-l));
      float k = s + bias[e];
      float ck = k, cv = s; int ci = e;
#pragma unroll
      for (int j = 0; j < 8; ++j) {
        bool g = ck > key[j];
        float tk = key[j], tv = sv[j]; int ti = idx[j];
        key[j] = g ? ck : tk; sv[j] = g ? cv : tv; idx[j] = g ? ci : ti;
        ck = g ? tk : ck;     cv = g ? tv : cv;    ci = g ? ti : ci;
      }
    }
    float sum = 1e-20f;
#pragma unroll
    for (int j = 0; j < 8; ++j) sum += sv[j];
    float inv = 1.0f / sum;
#pragma unroll
    for (int j = 0; j < 8; ++j) {
      out_scores[gt * 8 + j] = sv[j] * inv;
      out_idx[gt * 8 + j]    = (float)idx[j];
      atomicAdd(&counts[idx[j]], 1.0f);
    }
  }
}

extern "C" void kernel_launch(void* const* d_in, const int* in_sizes, int n_in,
                              void* d_out, int out_size, void* d_ws, size_t ws_size,
                              hipStream_t stream) {
  const float* x    = (const float*)d_in[0];
  const float* w    = (const float*)d_in[1];
  const float* bias = (const float*)d_in[2];

  const int ntok = in_sizes[0] / DIM;              // 16384
  float* out        = (float*)d_out;
  float* out_scores = out;
  float* out_idx    = out + ntok * 8;
  float* counts     = out + 2 * ntok * 8;

  hipMemsetAsync(counts, 0, NE * sizeof(float), stream);

  const size_t wsp_bytes = (size_t)8 * ntok * 64 * sizeof(float);  // 32 MB
  const size_t need = WSB_BYTES + wsp_bytes;

  if (ws_size >= need && (ntok % 512) == 0) {
    ushort* wsB = (ushort*)d_ws;
    float*  wsP = (float*)((char*)d_ws + WSB_BYTES);
    hipLaunchKernelGGL(pack_w, dim3(256), dim3(256), 0, stream, w, wsB);
    hipLaunchKernelGGL(router_k2, dim3(8 * (ntok / 512)), dim3(512), 0, stream,
                       x, (const uint4*)wsB, wsP, ntok);
    hipLaunchKernelGGL(router_k3, dim3(ntok / 128), dim3(128), 0, stream,
                       wsP, bias, out_scores, out_idx, counts, ntok);
  } else if (ws_size >= WSB_BYTES) {
    ushort* wsB = (ushort*)d_ws;
    hipLaunchKernelGGL(pack_w, dim3(256), dim3(256), 0, stream, w, wsB);
    hipLaunchKernelGGL(router_mfma, dim3(ntok / 64), dim3(512), 0, stream,
                       x, wsB, bias, out_scores, out_idx, counts);
  } else {
    hipLaunchKernelGGL(router_fallback, dim3(ntok / 64), dim3(512), 0, stream,
                       x, w, bias, out_scores, out_idx, counts);
  }
}

// Round 8
// 268.133 us; speedup vs baseline: 2.0323x; 2.0323x over previous
//
#include <hip/hip_runtime.h>
#include <math.h>

// TokenChoiceTopKRouter, round 8: R7 minus the atomic wall.
//
// R7 evidence: k3 = 339 us at 0.65% VALU / 60 GB/s -> the 131072 global fp32
// atomicAdds onto 64 counters (2-4 cache lines) serialize at L2. Fix: k3
// accumulates a per-block LDS histogram -> wsH[block][64]; new k5 reduces
// 128x64 partials into counts (no atomics, deterministic). k2 is UNCHANGED
// so its counters surface next round (it is the remaining ~190 us).
//
// Pipeline: pack_w -> k2 (K-split MFMA GEMM, partials) -> k3 (reduce+topk
// +hist) -> k5 (hist reduce). Fallbacks: R6 fused MFMA path; R5 fp32 path.

constexpr int DIM = 4096;
constexpr int NE  = 64;
constexpr size_t WSB_BYTES = 1048576;            // packed B stream (1 MB)

typedef __attribute__((ext_vector_type(8))) short bf16x8;
typedef __attribute__((ext_vector_type(4))) float f32x4;

// ---------- k1: pack w into per-K-slice hi/lo B-fragment stream ----------
// 16B-unit u = ks*8192 + sl*512 + f*64 + lane, f = et*2 + hl.
// Content: e = et*16 + (lane&15), k = ks*512 + sl*32 + 8*(lane>>4) (+j).
__global__ void pack_w(const float* __restrict__ w, ushort* __restrict__ wsB) {
  const int u  = blockIdx.x * 256 + threadIdx.x;   // 65536 units
  const int l  = u & 63;
  const int f  = (u >> 6) & 7;
  const int sl = (u >> 9) & 15;
  const int ks = u >> 13;
  const int et = f >> 1, hl = f & 1;
  const int e  = et * 16 + (l & 15);
  const int k  = ks * 512 + sl * 32 + 8 * (l >> 4);
  const float* src = w + (size_t)e * DIM + k;
  ushort v[8];
#pragma unroll
  for (int j = 0; j < 8; ++j) {
    float xv = src[j];
    unsigned xb = __float_as_uint(xv);
    unsigned hb = xb & 0xffff0000u;                // exact hi (truncation)
    if (hl == 0) {
      v[j] = (ushort)(hb >> 16);
    } else {
      float lf = xv - __uint_as_float(hb);
      unsigned lb = __float_as_uint(lf);
      lb = lb + 0x7fffu + ((lb >> 16) & 1u);       // RNE to bf16
      v[j] = (ushort)(lb >> 16);
    }
  }
  ushort* d = wsB + (size_t)u * 8;
#pragma unroll
  for (int j = 0; j < 8; ++j) d[j] = v[j];
}

// ---------- shared helper: f32x8 -> hi/lo bf16x8 ----------
__device__ __forceinline__ void split8(const float4& a0, const float4& a1,
                                       bf16x8& ahi, bf16x8& alo) {
  float av[8] = {a0.x, a0.y, a0.z, a0.w, a1.x, a1.y, a1.z, a1.w};
#pragma unroll
  for (int j = 0; j < 8; ++j) {
    unsigned xb = __float_as_uint(av[j]);
    unsigned hb = xb & 0xffff0000u;
    float lf = av[j] - __uint_as_float(hb);
    unsigned lb = __float_as_uint(lf);
    lb = lb + 0x7fffu + ((lb >> 16) & 1u);
    ahi[j] = (short)(hb >> 16);
    alo[j] = (short)(lb >> 16);
  }
}

// ---------- k2: main GEMM, B stationary in LDS, partials to ws (UNCHANGED) --
__global__ __launch_bounds__(512, 1)
void router_k2(const float* __restrict__ x, const uint4* __restrict__ wsB,
               float* __restrict__ wsP, int ntok) {
  __shared__ uint4 ldsB[8192];                    // 128 KB B-slice
  const int tid  = threadIdx.x;
  const int ks   = blockIdx.x & 7;                // == XCD id (L2-local B)
  const int tg   = blockIdx.x >> 3;
  const int wave = tid >> 6;
  const int lane = tid & 63;
  const int col  = lane & 15;                     // token col / expert col
  const int kq   = lane >> 4;                     // k-quad

  // stage B-slice once (coalesced global, linear LDS)
  const uint4* src = wsB + (size_t)ks * 8192;
#pragma unroll
  for (int it = 0; it < 16; ++it) ldsB[it * 512 + tid] = src[it * 512 + tid];
  __syncthreads();

  const bf16x8* B16 = (const bf16x8*)ldsB;
  const int t0w = tg * 512 + wave * 64;

#pragma unroll 1
  for (int tile = 0; tile < 4; ++tile) {
    const int t0 = t0w + tile * 16;
    const float* xr = x + (size_t)(t0 + col) * DIM + ks * 512 + 8 * kq;

    f32x4 acc[4];
#pragma unroll
    for (int et = 0; et < 4; ++et) acc[et] = (f32x4){0.f, 0.f, 0.f, 0.f};

    float4 pa[16], pb[16];                        // static-indexed (full unroll)
#pragma unroll
    for (int s = 0; s < 6; ++s) {                 // prologue: depth-6 prefetch
      pa[s] = *(const float4*)(xr + s * 32);
      pb[s] = *(const float4*)(xr + s * 32 + 4);
    }

#pragma unroll
    for (int s = 0; s < 16; ++s) {
      if (s + 6 < 16) {
        pa[s + 6] = *(const float4*)(xr + (s + 6) * 32);
        pb[s + 6] = *(const float4*)(xr + (s + 6) * 32 + 4);
      }
      bf16x8 ahi, alo;
      split8(pa[s], pb[s], ahi, alo);
#pragma unroll
      for (int et = 0; et < 4; ++et) {
        bf16x8 bh = B16[(s * 8 + et * 2 + 0) * 64 + lane];
        bf16x8 bl = B16[(s * 8 + et * 2 + 1) * 64 + lane];
        acc[et] = __builtin_amdgcn_mfma_f32_16x16x32_bf16(ahi, bh, acc[et], 0, 0, 0);
        acc[et] = __builtin_amdgcn_mfma_f32_16x16x32_bf16(alo, bh, acc[et], 0, 0, 0);
        acc[et] = __builtin_amdgcn_mfma_f32_16x16x32_bf16(ahi, bl, acc[et], 0, 0, 0);
      }
    }

    // partials: D layout col=lane&15, row=4*kq+r (m89-verified, R6-proven)
    float* dst = wsP + (size_t)ks * ntok * 64;
#pragma unroll
    for (int et = 0; et < 4; ++et)
#pragma unroll
      for (int r = 0; r < 4; ++r)
        dst[(size_t)(t0 + 4 * kq + r) * 64 + et * 16 + col] = acc[et][r];
  }
}

// ---------- k3: reduce K-slices + sigmoid + top-8 + LDS histogram ----------
__global__ __launch_bounds__(128, 1)
void router_k3(const float* __restrict__ wsP, const float* __restrict__ bias,
               float* __restrict__ out_scores, float* __restrict__ out_idx,
               float* __restrict__ wsH, int ntok) {
  __shared__ float hist[NE];
  if (threadIdx.x < NE) hist[threadIdx.x] = 0.f;
  __syncthreads();

  const int t = blockIdx.x * 128 + threadIdx.x;
  float a[64];
#pragma unroll
  for (int j = 0; j < 16; ++j) {
    f32x4 v = *(const f32x4*)(wsP + (size_t)t * 64 + j * 4);
    a[4 * j + 0] = v[0]; a[4 * j + 1] = v[1];
    a[4 * j + 2] = v[2]; a[4 * j + 3] = v[3];
  }
#pragma unroll
  for (int ks = 1; ks < 8; ++ks) {
#pragma unroll
    for (int j = 0; j < 16; ++j) {
      f32x4 v = *(const f32x4*)(wsP + (size_t)ks * ntok * 64 + (size_t)t * 64 + j * 4);
      a[4 * j + 0] += v[0]; a[4 * j + 1] += v[1];
      a[4 * j + 2] += v[2]; a[4 * j + 3] += v[3];
    }
  }

  float key[8], sv[8];
  int   idx[8];
#pragma unroll
  for (int j = 0; j < 8; ++j) { key[j] = -1e30f; sv[j] = 0.f; idx[j] = 0; }

#pragma unroll
  for (int e = 0; e < NE; ++e) {
    float s = 1.0f / (1.0f + expf(-a[e]));
    float k = s + bias[e];
    // bubble-insert; strict > keeps lower index on ties (lax.top_k order)
    float ck = k, cv = s; int ci = e;
#pragma unroll
    for (int j = 0; j < 8; ++j) {
      bool g = ck > key[j];
      float tk = key[j], tv = sv[j]; int ti = idx[j];
      key[j] = g ? ck : tk; sv[j] = g ? cv : tv; idx[j] = g ? ci : ti;
      ck = g ? tk : ck;     cv = g ? tv : cv;    ci = g ? ti : ci;
    }
  }

  float sum = 1e-20f;
#pragma unroll
  for (int j = 0; j < 8; ++j) sum += sv[j];
  float inv = 1.0f / sum;
#pragma unroll
  for (int j = 0; j < 8; ++j) {
    out_scores[t * 8 + j] = sv[j] * inv;
    out_idx[t * 8 + j]    = (float)idx[j];
    atomicAdd(&hist[idx[j]], 1.0f);       // LDS atomic: 64 bins, cheap
  }
  __syncthreads();
  if (threadIdx.x < NE) wsH[(size_t)blockIdx.x * NE + threadIdx.x] = hist[threadIdx.x];
}

// ---------- k5: reduce per-block histograms -> counts (no atomics) ----------
__global__ __launch_bounds__(64)
void router_k5(const float* __restrict__ wsH, float* __restrict__ counts,
               int nblk) {
  const int e = threadIdx.x;              // 0..63
  float s = 0.f;
  for (int b = 0; b < nblk; ++b) s += wsH[(size_t)b * NE + e];
  counts[e] = s;
}

// ---------- R6 proven mid-fallback (ws >= 1 MB): direct B-stream MFMA ------
__global__ __launch_bounds__(512, 2)
void router_mfma(const float* __restrict__ x, const ushort* __restrict__ ws,
                 const float* __restrict__ bias,
                 float* __restrict__ out_scores, float* __restrict__ out_idx,
                 float* __restrict__ counts) {
  __shared__ float logits[64 * 64];
  const int tid  = threadIdx.x;
  const int lane = tid & 63;
  const int wv   = tid >> 6;
  const int wt   = wv & 3;
  const int wk   = wv >> 2;
  const int tok0 = blockIdx.x * 64;
  const int col  = lane & 15;
  const int kq   = lane >> 4;
  const float* xrow = x + (size_t)(tok0 + wt * 16 + col) * DIM + wk * 2048 + 8 * kq;
  const ushort* wsl = ws + (size_t)lane * 8;
  f32x4 acc[4];
#pragma unroll
  for (int et = 0; et < 4; ++et) acc[et] = (f32x4){0.f, 0.f, 0.f, 0.f};
  const int s0 = wk * 64;
  float4 a0c = *(const float4*)(xrow + 0);
  float4 a1c = *(const float4*)(xrow + 4);
  bf16x8 bc[8];
#pragma unroll
  for (int f = 0; f < 8; ++f)
    bc[f] = *(const bf16x8*)(wsl + (size_t)(s0 * 8 + f) * 64 * 8);
#pragma unroll 1
  for (int ls = 0; ls < 64; ls += 2) {
    const int so = s0 + ls + 1;
    float4 a0o = *(const float4*)(xrow + (ls + 1) * 32);
    float4 a1o = *(const float4*)(xrow + (ls + 1) * 32 + 4);
    bf16x8 bo[8];
#pragma unroll
    for (int f = 0; f < 8; ++f)
      bo[f] = *(const bf16x8*)(wsl + (size_t)(so * 8 + f) * 64 * 8);
    {
      bf16x8 ahi, alo;
      split8(a0c, a1c, ahi, alo);
#pragma unroll
      for (int et = 0; et < 4; ++et) {
        acc[et] = __builtin_amdgcn_mfma_f32_16x16x32_bf16(ahi, bc[et * 2 + 0], acc[et], 0, 0, 0);
        acc[et] = __builtin_amdgcn_mfma_f32_16x16x32_bf16(alo, bc[et * 2 + 0], acc[et], 0, 0, 0);
        acc[et] = __builtin_amdgcn_mfma_f32_16x16x32_bf16(ahi, bc[et * 2 + 1], acc[et], 0, 0, 0);
      }
    }
    if (ls + 2 < 64) {
      const int se = s0 + ls + 2;
      a0c = *(const float4*)(xrow + (ls + 2) * 32);
      a1c = *(const float4*)(xrow + (ls + 2) * 32 + 4);
#pragma unroll
      for (int f = 0; f < 8; ++f)
        bc[f] = *(const bf16x8*)(wsl + (size_t)(se * 8 + f) * 64 * 8);
    }
    {
      bf16x8 ahi, alo;
      split8(a0o, a1o, ahi, alo);
#pragma unroll
      for (int et = 0; et < 4; ++et) {
        acc[et] = __builtin_amdgcn_mfma_f32_16x16x32_bf16(ahi, bo[et * 2 + 0], acc[et], 0, 0, 0);
        acc[et] = __builtin_amdgcn_mfma_f32_16x16x32_bf16(alo, bo[et * 2 + 0], acc[et], 0, 0, 0);
        acc[et] = __builtin_amdgcn_mfma_f32_16x16x32_bf16(ahi, bo[et * 2 + 1], acc[et], 0, 0, 0);
      }
    }
  }
  if (wk == 0) {
#pragma unroll
    for (int et = 0; et < 4; ++et)
#pragma unroll
      for (int r = 0; r < 4; ++r) {
        int t = wt * 16 + 4 * kq + r;
        int e = et * 16 + col;
        logits[t * 64 + ((e + t) & 63)] = acc[et][r];
      }
  }
  __syncthreads();
  if (wk == 1) {
#pragma unroll
    for (int et = 0; et < 4; ++et)
#pragma unroll
      for (int r = 0; r < 4; ++r) {
        int t = wt * 16 + 4 * kq + r;
        int e = et * 16 + col;
        logits[t * 64 + ((e + t) & 63)] += acc[et][r];
      }
  }
  __syncthreads();
  if (tid < 64) {
    const int t = tid, gt = tok0 + t;
    float key[8], sv[8]; int idx[8];
#pragma unroll
    for (int j = 0; j < 8; ++j) { key[j] = -1e30f; sv[j] = 0.f; idx[j] = 0; }
    for (int e = 0; e < NE; ++e) {
      float l = logits[t * 64 + ((e + t) & 63)];
      float s = 1.0f / (1.0f + expf(-l));
      float k = s + bias[e];
      float ck = k, cv = s; int ci = e;
#pragma unroll
      for (int j = 0; j < 8; ++j) {
        bool g = ck > key[j];
        float tk = key[j], tv = sv[j]; int ti = idx[j];
        key[j] = g ? ck : tk; sv[j] = g ? cv : tv; idx[j] = g ? ci : ti;
        ck = g ? tk : ck;     cv = g ? tv : cv;    ci = g ? ti : ci;
      }
    }
    float sum = 1e-20f;
#pragma unroll
    for (int j = 0; j < 8; ++j) sum += sv[j];
    float inv = 1.0f / sum;
#pragma unroll
    for (int j = 0; j < 8; ++j) {
      out_scores[gt * 8 + j] = sv[j] * inv;
      out_idx[gt * 8 + j]    = (float)idx[j];
      atomicAdd(&counts[idx[j]], 1.0f);
    }
  }
}

// ---------- R5 proven last-resort fallback (fp32 scalar-w) ----------
constexpr int KSTEP = 32;
constexpr int FNSTEP = DIM / KSTEP;
constexpr int ROWF4 = 9;
constexpr int BUF4  = 64 * ROWF4;

__global__ __launch_bounds__(512, 2)
void router_fallback(const float* __restrict__ x, const float* __restrict__ w,
                     const float* __restrict__ bias,
                     float* __restrict__ out_scores, float* __restrict__ out_idx,
                     float* __restrict__ counts) {
  __shared__ float4 lds4[2 * BUF4];
  float* ldsf = (float*)lds4;
  const int tid  = threadIdx.x;
  const int lane = tid & 63;
  const int eg   = __builtin_amdgcn_readfirstlane(tid >> 6);
  const int tok0 = blockIdx.x * 64;
  const int r0 = tid >> 3, j0 = tid & 7;
  const float* gp = &x[(size_t)(tok0 + r0) * DIM + j0 * 4];
  const int l0 = r0 * ROWF4 + j0;
  float acc[8];
#pragma unroll
  for (int e = 0; e < 8; ++e) acc[e] = 0.f;
  lds4[l0] = *(const float4*)gp;
  __syncthreads();
  const float* wbase = w + (size_t)eg * 8 * DIM;
#pragma unroll 1
  for (int c = 0; c < FNSTEP; ++c) {
    float4 pf;
    if (c + 1 < FNSTEP) pf = *(const float4*)(gp + (c + 1) * KSTEP);
    float xr[KSTEP];
    {
      const float4* xrow = lds4 + (c & 1) * BUF4 + lane * ROWF4;
#pragma unroll
      for (int i = 0; i < 8; ++i) {
        float4 q = xrow[i];
        xr[4 * i + 0] = q.x; xr[4 * i + 1] = q.y;
        xr[4 * i + 2] = q.z; xr[4 * i + 3] = q.w;
      }
    }
#pragma unroll
    for (int e = 0; e < 8; ++e) {
      const float* wr = wbase + e * DIM + c * KSTEP;
#pragma unroll
      for (int k = 0; k < KSTEP; ++k) acc[e] = fmaf(xr[k], wr[k], acc[e]);
    }
    if (c + 1 < FNSTEP) lds4[((c + 1) & 1) * BUF4 + l0] = pf;
    __syncthreads();
  }
#pragma unroll
  for (int j = 0; j < 8; ++j) {
    int e = eg * 8 + j;
    ldsf[lane * 64 + ((e + lane) & 63)] = acc[j];
  }
  __syncthreads();
  if (tid < 64) {
    const int t = tid, gt = tok0 + t;
    float key[8], sv[8]; int idx[8];
#pragma unroll
    for (int j = 0; j < 8; ++j) { key[j] = -1e30f; sv[j] = 0.f; idx[j] = 0; }
    for (int e = 0; e < NE; ++e) {
      float l = ldsf[t * 64 + ((e + t) & 63)];
      float s = 1.0f / (1.0f + expf(-l));
      float k = s + bias[e];
      float ck = k, cv = s; int ci = e;
#pragma unroll
      for (int j = 0; j < 8; ++j) {
        bool g = ck > key[j];
        float tk = key[j], tv = sv[j]; int ti = idx[j];
        key[j] = g ? ck : tk; sv[j] = g ? cv : tv; idx[j] = g ? ci : ti;
        ck = g ? tk : ck;     cv = g ? tv : cv;    ci = g ? ti : ci;
      }
    }
    float sum = 1e-20f;
#pragma unroll
    for (int j = 0; j < 8; ++j) sum += sv[j];
    float inv = 1.0f / sum;
#pragma unroll
    for (int j = 0; j < 8; ++j) {
      out_scores[gt * 8 + j] = sv[j] * inv;
      out_idx[gt * 8 + j]    = (float)idx[j];
      atomicAdd(&counts[idx[j]], 1.0f);
    }
  }
}

extern "C" void kernel_launch(void* const* d_in, const int* in_sizes, int n_in,
                              void* d_out, int out_size, void* d_ws, size_t ws_size,
                              hipStream_t stream) {
  const float* x    = (const float*)d_in[0];
  const float* w    = (const float*)d_in[1];
  const float* bias = (const float*)d_in[2];

  const int ntok = in_sizes[0] / DIM;              // 16384
  float* out        = (float*)d_out;
  float* out_scores = out;
  float* out_idx    = out + ntok * 8;
  float* counts     = out + 2 * ntok * 8;

  hipMemsetAsync(counts, 0, NE * sizeof(float), stream);

  const int    nblk3     = ntok / 128;
  const size_t wsp_bytes = (size_t)8 * ntok * 64 * sizeof(float);   // 32 MB
  const size_t wsh_bytes = (size_t)nblk3 * NE * sizeof(float);      // 32 KB
  const size_t need = WSB_BYTES + wsp_bytes + wsh_bytes;

  if (ws_size >= need && (ntok % 512) == 0) {
    ushort* wsB = (ushort*)d_ws;
    float*  wsP = (float*)((char*)d_ws + WSB_BYTES);
    float*  wsH = (float*)((char*)d_ws + WSB_BYTES + wsp_bytes);
    hipLaunchKernelGGL(pack_w, dim3(256), dim3(256), 0, stream, w, wsB);
    hipLaunchKernelGGL(router_k2, dim3(8 * (ntok / 512)), dim3(512), 0, stream,
                       x, (const uint4*)wsB, wsP, ntok);
    hipLaunchKernelGGL(router_k3, dim3(nblk3), dim3(128), 0, stream,
                       wsP, bias, out_scores, out_idx, wsH, ntok);
    hipLaunchKernelGGL(router_k5, dim3(1), dim3(64), 0, stream,
                       wsH, counts, nblk3);
  } else if (ws_size >= WSB_BYTES) {
    ushort* wsB = (ushort*)d_ws;
    hipLaunchKernelGGL(pack_w, dim3(256), dim3(256), 0, stream, w, wsB);
    hipLaunchKernelGGL(router_mfma, dim3(ntok / 64), dim3(512), 0, stream,
                       x, wsB, bias, out_scores, out_idx, counts);
  } else {
    hipLaunchKernelGGL(router_fallback, dim3(ntok / 64), dim3(512), 0, stream,
                       x, w, bias, out_scores, out_idx, counts);
  }
}